// Round 1
// 4180.819 us; speedup vs baseline: 1.0906x; 1.0906x over previous
//
#include <hip/hip_runtime.h>

typedef _Float16 f16;
typedef _Float16 f16x8 __attribute__((ext_vector_type(8)));
typedef float f32x4 __attribute__((ext_vector_type(4)));

// dims
#define BB 16
#define TT 128
#define VV 32000
#define EE 400
#define HH 1150
#define MM 2048   // T*B rows

#define NWG1 144          // layer1 blocks (4608/32)
#define NWG2 144          // layer2 blocks
#define NWG3 52           // layer3 blocks (1664/32)
#define NSTEPS 130        // 128 + 2 pipeline-fill steps

__device__ __forceinline__ float sigm(float x){ return 1.f/(1.f + __expf(-x)); }
__device__ __forceinline__ float ftanh(float x){ return 2.f/(1.f + __expf(-2.f*x)) - 1.f; }

// ---------------- conversion kernels ----------------

__global__ void conv_emb(const float* __restrict__ src, f16* __restrict__ dst){
    int v = blockIdx.y;
    int k = blockIdx.x*256 + threadIdx.x;
    if (k >= 416) return;
    float val = (k < EE) ? src[v*EE + k] : 0.f;
    dst[v*416 + k] = (f16)val;
}

__global__ void embed_gather(const float* __restrict__ emb, const int* __restrict__ x,
                             f16* __restrict__ dst){
    int m = blockIdx.y;            // t*16+b
    int k = blockIdx.x*256 + threadIdx.x;
    if (k >= 416) return;
    int t = m >> 4, b = m & 15;
    int row = x[b*TT + t];
    float val = (k < EE) ? emb[row*EE + k] : 0.f;
    dst[m*416 + k] = (f16)val;
}

// W (4*Hout, Ksrc) f32 -> dst (Np, Kp) f16, dst row n = j*4+g  <- src row g*Hout+j
__global__ void conv_w(const float* __restrict__ src, f16* __restrict__ dst,
                       int Hout, int Ksrc, int Kp){
    int n = blockIdx.y;
    int k = blockIdx.x*256 + threadIdx.x;
    if (k >= Kp) return;
    int j = n >> 2, g = n & 3;
    float val = (j < Hout && k < Ksrc) ? src[(g*Hout + j)*Ksrc + k] : 0.f;
    dst[(size_t)n*Kp + k] = (f16)val;
}

__global__ void conv_bias(const float* __restrict__ bi, const float* __restrict__ bh,
                          float* __restrict__ dst, int Hout, int Np){
    int n = blockIdx.x*256 + threadIdx.x;
    if (n >= Np) return;
    int j = n >> 2, g = n & 3;
    dst[n] = (j < Hout) ? (bi[g*Hout + j] + bh[g*Hout + j]) : 0.f;
}

// ---------------- GEMM: C(M,N) = A(M,Kp) * B(N,Kp)^T + bias ----------------
template<int SC>
__global__ __launch_bounds__(256) void gemm16(
    const f16* __restrict__ A, const f16* __restrict__ B,
    const float* __restrict__ bias, float* __restrict__ C,
    int Kp, int Nst)
{
    __shared__ __align__(16) f16 lA[128*32];
    __shared__ __align__(16) f16 lB[128*32];
    const int lane = threadIdx.x & 63;
    const int wid  = threadIdx.x >> 6;
    const int m0 = blockIdx.y * 128, n0 = blockIdx.x * 128;
    f32x4 acc[4][4] = {};
    const int sr = threadIdx.x >> 2;
    const int sc = (threadIdx.x & 3) * 8;
    for (int k0 = 0; k0 < Kp; k0 += 32) {
        __syncthreads();
        *(f16x8*)&lA[ sr      *32 + sc] = *(const f16x8*)&A[(size_t)(m0 + sr     )*Kp + k0 + sc];
        *(f16x8*)&lA[(sr + 64)*32 + sc] = *(const f16x8*)&A[(size_t)(m0 + sr + 64)*Kp + k0 + sc];
        *(f16x8*)&lB[ sr      *32 + sc] = *(const f16x8*)&B[(size_t)(n0 + sr     )*Kp + k0 + sc];
        *(f16x8*)&lB[(sr + 64)*32 + sc] = *(const f16x8*)&B[(size_t)(n0 + sr + 64)*Kp + k0 + sc];
        __syncthreads();
        const int wr = (wid >> 1) * 64, wc = (wid & 1) * 64;
        f16x8 af[4], bf[4];
        #pragma unroll
        for (int i = 0; i < 4; ++i)
            af[i] = *(const f16x8*)&lA[(wr + i*16 + (lane & 15))*32 + (lane >> 4)*8];
        #pragma unroll
        for (int j = 0; j < 4; ++j)
            bf[j] = *(const f16x8*)&lB[(wc + j*16 + (lane & 15))*32 + (lane >> 4)*8];
        #pragma unroll
        for (int i = 0; i < 4; ++i)
            #pragma unroll
            for (int j = 0; j < 4; ++j)
                acc[i][j] = __builtin_amdgcn_mfma_f32_16x16x32_f16(af[i], bf[j], acc[i][j], 0, 0, 0);
    }
    const int wr = (wid >> 1) * 64, wc = (wid & 1) * 64;
    #pragma unroll
    for (int i = 0; i < 4; ++i) {
        #pragma unroll
        for (int j = 0; j < 4; ++j) {
            int gc = n0 + wc + j*16 + (lane & 15);
            float bb = bias[gc];
            #pragma unroll
            for (int r = 0; r < 4; ++r) {
                int gr = m0 + wr + i*16 + (lane >> 4)*4 + r;
                float v = acc[i][j][r] + bb;
                if (SC) C[((size_t)(gr >> 7)*VV + gc)*TT + (gr & 127)] = v;   // out[b][v][t]
                else    C[(size_t)gr*Nst + gc] = v;
            }
        }
    }
}

// ---------------- pipelined persistent 3-layer LSTM ----------------
// One grid of NWG1+NWG2+NWG3 blocks. Global step s: layer1 does t=s,
// layer2 t=s-1 (reads layer1's h ping-pong directly as its x input),
// layer3 t=s-2. One global spin-barrier per step -> 130 sequential
// barriers instead of 384. Input GEMV (x @ W_ih) for layers 2/3 is
// computed in-kernel from register-resident packed W_ih.
// Parity convention (matches prior kernel): step t reads (t&1)?B:A,
// writes the other; so h_t lives in (t&1)?A:B.

template<int KIH, int KHH, int DELAY>
__device__ __forceinline__ void lstm_role(
    float (&red)[4][16][32], float (&cst)[16][8],
    const float* __restrict__ pre,     // L1 only (KIH==0): (2048,4608) rows t*16+b, bias folded in
    const float* __restrict__ bias,    // L2/L3: packed (Np)
    const f16* __restrict__ Wih,       // (Np,1152) packed, KIH>0 only
    const f16* __restrict__ Whh,       // (Np,HpHH) packed
    const f16* __restrict__ xA, const f16* __restrict__ xB,  // producer h ping-pong
    f16* __restrict__ hA, f16* __restrict__ hB,              // own h ping-pong
    f16* __restrict__ xs3,             // L3 only: (b*TT+t)*416+j
    float* __restrict__ hout, float* __restrict__ cout,
    unsigned* __restrict__ arrive, int bid, int H)
{
    constexpr int HpHH = KHH * 128;
    constexpr int KIHA = (KIH > 0) ? KIH : 1;
    const int lane = threadIdx.x & 63, kw = threadIdx.x >> 6;
    const int n0 = bid * 32;
    const int nwg = gridDim.x;
    if (threadIdx.x < 128) cst[threadIdx.x & 15][threadIdx.x >> 4] = 0.f;
    const int arow = lane & 15, aoff = (lane >> 4) * 8;
    const size_t hofsHH = (size_t)arow * HpHH + kw * (KHH * 32) + aoff;
    const size_t hofsIH = (size_t)arow * 1152 + kw * 288 + aoff;

    // register-resident weights (land in unified VGPR/AGPR file)
    f16x8 wh0[KHH], wh1[KHH];
    {
        const f16* wp0 = Whh + (size_t)(n0 + arow) * HpHH + kw * (KHH * 32) + aoff;
        const f16* wp1 = wp0 + (size_t)16 * HpHH;
        #pragma unroll
        for (int i = 0; i < KHH; ++i) {
            wh0[i] = *(const f16x8*)(wp0 + i*32);
            wh1[i] = *(const f16x8*)(wp1 + i*32);
        }
    }
    f16x8 wi0[KIHA], wi1[KIHA];
    if constexpr (KIH > 0) {
        const f16* wp0 = Wih + (size_t)(n0 + arow) * 1152 + kw * 288 + aoff;
        const f16* wp1 = wp0 + (size_t)16 * 1152;
        #pragma unroll
        for (int i = 0; i < KIH; ++i) {
            wi0[i] = *(const f16x8*)(wp0 + i*32);
            wi1[i] = *(const f16x8*)(wp1 + i*32);
        }
    }
    const int b  = threadIdx.x & 15;
    const int jl = threadIdx.x >> 4;      // 0..7 when tid<128
    f32x4 bias4 = {0.f,0.f,0.f,0.f};
    if constexpr (KIH > 0) {
        if (threadIdx.x < 128) bias4 = *(const f32x4*)(bias + n0 + jl*4);
    }
    __syncthreads();

    for (int s = 0; s < NSTEPS; ++s) {
        const int t = s - DELAY;
        if (t >= 0 && t < TT) {
            const f16* hp = ((t & 1) ? hB : hA) + hofsHH;
            f16* hw       =  (t & 1) ? hA : hB;
            f32x4 p4;
            if constexpr (KIH == 0) {
                if (threadIdx.x < 128)
                    p4 = *(const f32x4*)(pre + (size_t)(t*16 + b)*4608 + n0 + jl*4);
            }
            f32x4 acc0 = {0.f,0.f,0.f,0.f}, acc1 = {0.f,0.f,0.f,0.f};
            if constexpr (KIH > 0) {
                const f16* xp = ((t & 1) ? xA : xB) + hofsIH;   // producer h_t
                #pragma unroll
                for (int i = 0; i < KIH; ++i) {
                    f16x8 av = *(const f16x8*)(xp + i*32);
                    acc0 = __builtin_amdgcn_mfma_f32_16x16x32_f16(av, wi0[i], acc0, 0, 0, 0);
                    acc1 = __builtin_amdgcn_mfma_f32_16x16x32_f16(av, wi1[i], acc1, 0, 0, 0);
                }
            }
            #pragma unroll
            for (int i = 0; i < KHH; ++i) {
                f16x8 av = *(const f16x8*)(hp + i*32);
                acc0 = __builtin_amdgcn_mfma_f32_16x16x32_f16(av, wh0[i], acc0, 0, 0, 0);
                acc1 = __builtin_amdgcn_mfma_f32_16x16x32_f16(av, wh1[i], acc1, 0, 0, 0);
            }
            #pragma unroll
            for (int r = 0; r < 4; ++r) {
                red[kw][(lane >> 4)*4 + r][lane & 15]        = acc0[r];
                red[kw][(lane >> 4)*4 + r][16 + (lane & 15)] = acc1[r];
            }
            __syncthreads();
            if (threadIdx.x < 128) {
                const int nb = jl * 4;
                f32x4 base = (KIH > 0) ? bias4 : p4;
                float gi = base[0] + red[0][b][nb+0] + red[1][b][nb+0] + red[2][b][nb+0] + red[3][b][nb+0];
                float gf = base[1] + red[0][b][nb+1] + red[1][b][nb+1] + red[2][b][nb+1] + red[3][b][nb+1];
                float gg = base[2] + red[0][b][nb+2] + red[1][b][nb+2] + red[2][b][nb+2] + red[3][b][nb+2];
                float go = base[3] + red[0][b][nb+3] + red[1][b][nb+3] + red[2][b][nb+3] + red[3][b][nb+3];
                float c = sigm(gf) * cst[b][jl] + sigm(gi) * ftanh(gg);
                float h = sigm(go) * ftanh(c);
                cst[b][jl] = c;
                const int j = (n0 >> 2) + jl;
                hw[b*HpHH + j] = (f16)h;
                if constexpr (DELAY == 2) xs3[(size_t)(b*TT + t)*416 + j] = (f16)h;
                if (t == TT-1 && j < H) { hout[b*H + j] = h; cout[b*H + j] = c; }
                __builtin_amdgcn_fence(__ATOMIC_RELEASE, "agent");   // flush h to LLC
            }
        }
        if (s == NSTEPS-1) break;     // last compute is L3's; kernel-end flushes
        __syncthreads();
        if (threadIdx.x == 0)
            __hip_atomic_store(&arrive[blockIdx.x * 16], (unsigned)(s + 1),
                               __ATOMIC_RELAXED, __HIP_MEMORY_SCOPE_AGENT);
        for (int w = threadIdx.x; w < nwg; w += 256) {
            while (__hip_atomic_load(&arrive[w * 16], __ATOMIC_RELAXED,
                                     __HIP_MEMORY_SCOPE_AGENT) < (unsigned)(s + 1))
                __builtin_amdgcn_s_sleep(1);
        }
        __syncthreads();
        __builtin_amdgcn_fence(__ATOMIC_ACQUIRE, "agent");           // one inv per step
    }
}

__global__ __launch_bounds__(256, 2) void lstm_mega(
    const float* __restrict__ pre1,
    const float* __restrict__ bias2, const float* __restrict__ bias3,
    const f16* __restrict__ whh1,
    const f16* __restrict__ wih2, const f16* __restrict__ whh2,
    const f16* __restrict__ wih3, const f16* __restrict__ whh3,
    f16* h1A, f16* h1B, f16* h2A, f16* h2B, f16* h3A, f16* h3B,
    f16* xs3,
    float* h1o, float* c1o, float* h2o, float* c2o, float* h3o, float* c3o,
    unsigned* arrive)
{
    __shared__ float red[4][16][32];
    __shared__ float cst[16][8];
    const int bx = blockIdx.x;
    if (bx < NWG1) {
        lstm_role<0,9,0>(red, cst, pre1, nullptr, nullptr, whh1,
                         nullptr, nullptr, h1A, h1B, nullptr,
                         h1o, c1o, arrive, bx, HH);
    } else if (bx < NWG1 + NWG2) {
        lstm_role<9,9,1>(red, cst, nullptr, bias2, wih2, whh2,
                         h1A, h1B, h2A, h2B, nullptr,
                         h2o, c2o, arrive, bx - NWG1, HH);
    } else {
        lstm_role<9,4,2>(red, cst, nullptr, bias3, wih3, whh3,
                         h2A, h2B, h3A, h3B, xs3,
                         h3o, c3o, arrive, bx - NWG1 - NWG2, EE);
    }
}

// ---------------- host ----------------
extern "C" void kernel_launch(void* const* d_in, const int* in_sizes, int n_in,
                              void* d_out, int out_size, void* d_ws, size_t ws_size,
                              hipStream_t stream)
{
    const float* emb  = (const float*)d_in[0];
    const float* Wih1 = (const float*)d_in[1];
    const float* Whh1 = (const float*)d_in[2];
    const float* bih1 = (const float*)d_in[3];
    const float* bhh1 = (const float*)d_in[4];
    const float* Wih2 = (const float*)d_in[5];
    const float* Whh2 = (const float*)d_in[6];
    const float* bih2 = (const float*)d_in[7];
    const float* bhh2 = (const float*)d_in[8];
    const float* Wih3 = (const float*)d_in[9];
    const float* Whh3 = (const float*)d_in[10];
    const float* bih3 = (const float*)d_in[11];
    const float* bhh3 = (const float*)d_in[12];
    const float* linb = (const float*)d_in[13];
    const int*   x    = (const int*)d_in[14];
    float* out = (float*)d_out;
    char*  ws  = (char*)d_ws;
    char*  outc = (char*)d_out;

    // ---- ws layout (zeroed region first: flags + 6 h ping-pong buffers) ----
    const size_t ARR  = 0;                          // 340*64 = 21760 B
    const size_t H1A  = 21760;                      // 16*1152*2 = 36864 each
    const size_t H1B  = H1A + 36864;
    const size_t H2A  = H1B + 36864;
    const size_t H2B  = H2A + 36864;
    const size_t H3A  = H2B + 36864;                // 16*512*2 = 16384 each
    const size_t H3B  = H3A + 16384;
    const size_t ZEND = H3B + 16384;                // 201984 (256-aligned)
    size_t off = ZEND;
    auto alloc = [&](size_t bytes){ size_t r = off; off += (bytes + 255) & ~(size_t)255; return r; };
    const size_t EMBBF = alloc((size_t)VV*416*2);   // 26.6 MB
    const size_t XS0   = alloc((size_t)MM*416*2);   // embedded input, f16
    const size_t XS3   = alloc((size_t)MM*416*2);   // layer3 output, f16
    const size_t WIH1  = alloc((size_t)4608*416*2); // packed for pre-GEMM
    const size_t B1    = alloc((size_t)4608*4);
    const size_t B2    = alloc((size_t)4608*4);
    const size_t B3    = alloc((size_t)1664*4);

    f16* emb_bf = (f16*)(ws + EMBBF);
    f16* xs0    = (f16*)(ws + XS0);
    f16* xs3    = (f16*)(ws + XS3);
    f16* wih1p  = (f16*)(ws + WIH1);
    float* bias1 = (float*)(ws + B1);
    float* bias2 = (float*)(ws + B2);
    float* bias3 = (float*)(ws + B3);
    unsigned* arr = (unsigned*)(ws + ARR);

    // ---- big scratch lives in the (dead-until-final-GEMM) out buffer ----
    float* pre1 = out;                               // 2048*4608*4 = 37,748,736 B
    const size_t OW_HH1 = 37748736;                  // 4608*1152*2 = 10,616,832
    const size_t OW_IH2 = OW_HH1 + 10616832;
    const size_t OW_HH2 = OW_IH2 + 10616832;
    const size_t OW_IH3 = OW_HH2 + 10616832;         // 1664*1152*2 = 3,833,856
    const size_t OW_HH3 = OW_IH3 + 3833856;          // 1664*512*2  = 1,703,936
    f16* whh1p = (f16*)(outc + OW_HH1);
    f16* wih2p = (f16*)(outc + OW_IH2);
    f16* whh2p = (f16*)(outc + OW_HH2);
    f16* wih3p = (f16*)(outc + OW_IH3);
    f16* whh3p = (f16*)(outc + OW_HH3);

    float* H1O = out + 65536000;  float* H2O = H1O + 18400;  float* H3O = H2O + 18400;
    float* C1O = H3O + 6400;      float* C2O = C1O + 18400;  float* C3O = C2O + 18400;

    hipMemsetAsync(d_ws, 0, ZEND, stream);

    conv_emb    <<<dim3(2, VV), 256, 0, stream>>>(emb, emb_bf);
    embed_gather<<<dim3(2, MM), 256, 0, stream>>>(emb, x, xs0);

    // layer-1 input pre-GEMM (input known upfront; stays a throughput GEMM)
    conv_w   <<<dim3(2, 4608), 256, 0, stream>>>(Wih1, wih1p, HH, EE, 416);
    conv_bias<<<dim3(18),      256, 0, stream>>>(bih1, bhh1, bias1, HH, 4608);
    gemm16<0><<<dim3(36, 16),  256, 0, stream>>>(xs0, wih1p, bias1, pre1, 416, 4608);

    // pack all recurrent-phase weights/biases
    conv_w   <<<dim3(5, 4608), 256, 0, stream>>>(Whh1, whh1p, HH, HH, 1152);
    conv_w   <<<dim3(5, 4608), 256, 0, stream>>>(Wih2, wih2p, HH, HH, 1152);
    conv_w   <<<dim3(5, 4608), 256, 0, stream>>>(Whh2, whh2p, HH, HH, 1152);
    conv_w   <<<dim3(5, 1664), 256, 0, stream>>>(Wih3, wih3p, EE, HH, 1152);
    conv_w   <<<dim3(2, 1664), 256, 0, stream>>>(Whh3, whh3p, EE, EE, 512);
    conv_bias<<<dim3(18),      256, 0, stream>>>(bih2, bhh2, bias2, HH, 4608);
    conv_bias<<<dim3(7),       256, 0, stream>>>(bih3, bhh3, bias3, EE, 1664);

    // pipelined 3-layer recurrence: 130 global barrier steps instead of 384
    lstm_mega<<<dim3(NWG1 + NWG2 + NWG3), 256, 0, stream>>>(
        pre1, bias2, bias3, whh1p, wih2p, whh2p, wih3p, whh3p,
        (f16*)(ws+H1A), (f16*)(ws+H1B), (f16*)(ws+H2A), (f16*)(ws+H2B),
        (f16*)(ws+H3A), (f16*)(ws+H3B),
        xs3, H1O, C1O, H2O, C2O, H3O, C3O, arr);

    // tied-weight logits with fused transpose to (B,V,T)
    gemm16<1><<<dim3(250, 16), 256, 0, stream>>>(xs3, emb_bf, linb, out, 416, 0);
}

// Round 2
// 4175.860 us; speedup vs baseline: 1.0919x; 1.0012x over previous
//
#include <hip/hip_runtime.h>

typedef _Float16 f16;
typedef _Float16 f16x8 __attribute__((ext_vector_type(8)));
typedef float f32x4 __attribute__((ext_vector_type(4)));

// dims
#define BB 16
#define TT 128
#define VV 32000
#define EE 400
#define HH 1150
#define MM 2048   // T*B rows

#define NWG1 144          // layer1 blocks (4608/32)
#define NWG2 144          // layer2 blocks
#define NWG3 52           // layer3 blocks (1664/32)
#define NSTEPS 130        // 128 + 2 pipeline-fill steps

// Break the def-use chain back to the load so the compiler CANNOT
// rematerialize weight loads inside the step loop (learn_hip rule #17).
#define PIN(v) asm volatile("" : "+v"(v))

__device__ __forceinline__ float sigm(float x){ return 1.f/(1.f + __expf(-x)); }
__device__ __forceinline__ float ftanh(float x){ return 2.f/(1.f + __expf(-2.f*x)) - 1.f; }

// ---------------- conversion kernels ----------------

__global__ void conv_emb(const float* __restrict__ src, f16* __restrict__ dst){
    int v = blockIdx.y;
    int k = blockIdx.x*256 + threadIdx.x;
    if (k >= 416) return;
    float val = (k < EE) ? src[v*EE + k] : 0.f;
    dst[v*416 + k] = (f16)val;
}

__global__ void embed_gather(const float* __restrict__ emb, const int* __restrict__ x,
                             f16* __restrict__ dst){
    int m = blockIdx.y;            // t*16+b
    int k = blockIdx.x*256 + threadIdx.x;
    if (k >= 416) return;
    int t = m >> 4, b = m & 15;
    int row = x[b*TT + t];
    float val = (k < EE) ? emb[row*EE + k] : 0.f;
    dst[m*416 + k] = (f16)val;
}

// W (4*Hout, Ksrc) f32 -> dst (Np, Kp) f16, dst row n = j*4+g  <- src row g*Hout+j
__global__ void conv_w(const float* __restrict__ src, f16* __restrict__ dst,
                       int Hout, int Ksrc, int Kp){
    int n = blockIdx.y;
    int k = blockIdx.x*256 + threadIdx.x;
    if (k >= Kp) return;
    int j = n >> 2, g = n & 3;
    float val = (j < Hout && k < Ksrc) ? src[(g*Hout + j)*Ksrc + k] : 0.f;
    dst[(size_t)n*Kp + k] = (f16)val;
}

__global__ void conv_bias(const float* __restrict__ bi, const float* __restrict__ bh,
                          float* __restrict__ dst, int Hout, int Np){
    int n = blockIdx.x*256 + threadIdx.x;
    if (n >= Np) return;
    int j = n >> 2, g = n & 3;
    dst[n] = (j < Hout) ? (bi[g*Hout + j] + bh[g*Hout + j]) : 0.f;
}

// ---------------- GEMM: C(M,N) = A(M,Kp) * B(N,Kp)^T + bias ----------------
template<int SC>
__global__ __launch_bounds__(256) void gemm16(
    const f16* __restrict__ A, const f16* __restrict__ B,
    const float* __restrict__ bias, float* __restrict__ C,
    int Kp, int Nst)
{
    __shared__ __align__(16) f16 lA[128*32];
    __shared__ __align__(16) f16 lB[128*32];
    const int lane = threadIdx.x & 63;
    const int wid  = threadIdx.x >> 6;
    const int m0 = blockIdx.y * 128, n0 = blockIdx.x * 128;
    f32x4 acc[4][4] = {};
    const int sr = threadIdx.x >> 2;
    const int sc = (threadIdx.x & 3) * 8;
    for (int k0 = 0; k0 < Kp; k0 += 32) {
        __syncthreads();
        *(f16x8*)&lA[ sr      *32 + sc] = *(const f16x8*)&A[(size_t)(m0 + sr     )*Kp + k0 + sc];
        *(f16x8*)&lA[(sr + 64)*32 + sc] = *(const f16x8*)&A[(size_t)(m0 + sr + 64)*Kp + k0 + sc];
        *(f16x8*)&lB[ sr      *32 + sc] = *(const f16x8*)&B[(size_t)(n0 + sr     )*Kp + k0 + sc];
        *(f16x8*)&lB[(sr + 64)*32 + sc] = *(const f16x8*)&B[(size_t)(n0 + sr + 64)*Kp + k0 + sc];
        __syncthreads();
        const int wr = (wid >> 1) * 64, wc = (wid & 1) * 64;
        f16x8 af[4], bf[4];
        #pragma unroll
        for (int i = 0; i < 4; ++i)
            af[i] = *(const f16x8*)&lA[(wr + i*16 + (lane & 15))*32 + (lane >> 4)*8];
        #pragma unroll
        for (int j = 0; j < 4; ++j)
            bf[j] = *(const f16x8*)&lB[(wc + j*16 + (lane & 15))*32 + (lane >> 4)*8];
        #pragma unroll
        for (int i = 0; i < 4; ++i)
            #pragma unroll
            for (int j = 0; j < 4; ++j)
                acc[i][j] = __builtin_amdgcn_mfma_f32_16x16x32_f16(af[i], bf[j], acc[i][j], 0, 0, 0);
    }
    const int wr = (wid >> 1) * 64, wc = (wid & 1) * 64;
    #pragma unroll
    for (int i = 0; i < 4; ++i) {
        #pragma unroll
        for (int j = 0; j < 4; ++j) {
            int gc = n0 + wc + j*16 + (lane & 15);
            float bb = bias[gc];
            #pragma unroll
            for (int r = 0; r < 4; ++r) {
                int gr = m0 + wr + i*16 + (lane >> 4)*4 + r;
                float v = acc[i][j][r] + bb;
                if (SC) C[((size_t)(gr >> 7)*VV + gc)*TT + (gr & 127)] = v;   // out[b][v][t]
                else    C[(size_t)gr*Nst + gc] = v;
            }
        }
    }
}

// ---------------- pipelined persistent 3-layer LSTM ----------------
// One grid of NWG1+NWG2+NWG3 blocks. Global step s: layer1 does t=s,
// layer2 t=s-1 (reads layer1's h ping-pong directly as its x input),
// layer3 t=s-2. One global spin-barrier per step -> 130 sequential
// barriers instead of 384. Weights are PINNED in registers (asm) so the
// per-step acquire fence / L2 invalidate cannot force a 37 MB/step
// LLC re-stream of the weight matrices (round-1 regression: VGPR=92
// proved the compiler rematerialized the weight loads in-loop).

template<int KIH, int KHH, int DELAY>
__device__ __forceinline__ void lstm_role(
    float (&red)[4][16][32], float (&cst)[16][8],
    const float* __restrict__ pre,     // L1 only (KIH==0): (2048,4608) rows t*16+b, bias folded in
    const float* __restrict__ bias,    // L2/L3: packed (Np)
    const f16* __restrict__ Wih,       // (Np,1152) packed, KIH>0 only
    const f16* __restrict__ Whh,       // (Np,HpHH) packed
    const f16* __restrict__ xA, const f16* __restrict__ xB,  // producer h ping-pong
    f16* __restrict__ hA, f16* __restrict__ hB,              // own h ping-pong
    f16* __restrict__ xs3,             // L3 only: (b*TT+t)*416+j
    float* __restrict__ hout, float* __restrict__ cout,
    unsigned* __restrict__ arrive, int bid, int H)
{
    constexpr int HpHH = KHH * 128;
    constexpr int KIHA = (KIH > 0) ? KIH : 1;
    const int lane = threadIdx.x & 63, kw = threadIdx.x >> 6;
    const int n0 = bid * 32;
    const int nwg = gridDim.x;
    if (threadIdx.x < 128) cst[threadIdx.x & 15][threadIdx.x >> 4] = 0.f;
    const int arow = lane & 15, aoff = (lane >> 4) * 8;
    const size_t hofsHH = (size_t)arow * HpHH + kw * (KHH * 32) + aoff;
    const size_t hofsIH = (size_t)arow * 1152 + kw * 288 + aoff;

    // register-resident weights (land in unified VGPR/AGPR file)
    f16x8 wh0[KHH], wh1[KHH];
    {
        const f16* wp0 = Whh + (size_t)(n0 + arow) * HpHH + kw * (KHH * 32) + aoff;
        const f16* wp1 = wp0 + (size_t)16 * HpHH;
        #pragma unroll
        for (int i = 0; i < KHH; ++i) {
            wh0[i] = *(const f16x8*)(wp0 + i*32);
            wh1[i] = *(const f16x8*)(wp1 + i*32);
        }
    }
    f16x8 wi0[KIHA], wi1[KIHA];
    if constexpr (KIH > 0) {
        const f16* wp0 = Wih + (size_t)(n0 + arow) * 1152 + kw * 288 + aoff;
        const f16* wp1 = wp0 + (size_t)16 * 1152;
        #pragma unroll
        for (int i = 0; i < KIH; ++i) {
            wi0[i] = *(const f16x8*)(wp0 + i*32);
            wi1[i] = *(const f16x8*)(wp1 + i*32);
        }
    }
    // pin: weights must stay live across the whole step loop
    #pragma unroll
    for (int i = 0; i < KHH; ++i) { PIN(wh0[i]); PIN(wh1[i]); }
    if constexpr (KIH > 0) {
        #pragma unroll
        for (int i = 0; i < KIH; ++i) { PIN(wi0[i]); PIN(wi1[i]); }
    }
    const int b  = threadIdx.x & 15;
    const int jl = threadIdx.x >> 4;      // 0..7 when tid<128
    f32x4 bias4 = {0.f,0.f,0.f,0.f};
    if constexpr (KIH > 0) {
        if (threadIdx.x < 128) bias4 = *(const f32x4*)(bias + n0 + jl*4);
    }
    __syncthreads();

    for (int s = 0; s < NSTEPS; ++s) {
        const int t = s - DELAY;
        if (t >= 0 && t < TT) {
            const f16* hp = ((t & 1) ? hB : hA) + hofsHH;
            f16* hw       =  (t & 1) ? hA : hB;
            f32x4 p4;
            if constexpr (KIH == 0) {
                if (threadIdx.x < 128)
                    p4 = *(const f32x4*)(pre + (size_t)(t*16 + b)*4608 + n0 + jl*4);
            }
            f32x4 acc0 = {0.f,0.f,0.f,0.f}, acc1 = {0.f,0.f,0.f,0.f};
            if constexpr (KIH > 0) {
                const f16* xp = ((t & 1) ? xA : xB) + hofsIH;   // producer h_t
                #pragma unroll
                for (int i = 0; i < KIH; ++i) {
                    f16x8 av = *(const f16x8*)(xp + i*32);
                    acc0 = __builtin_amdgcn_mfma_f32_16x16x32_f16(av, wi0[i], acc0, 0, 0, 0);
                    acc1 = __builtin_amdgcn_mfma_f32_16x16x32_f16(av, wi1[i], acc1, 0, 0, 0);
                }
            }
            #pragma unroll
            for (int i = 0; i < KHH; ++i) {
                f16x8 av = *(const f16x8*)(hp + i*32);
                acc0 = __builtin_amdgcn_mfma_f32_16x16x32_f16(av, wh0[i], acc0, 0, 0, 0);
                acc1 = __builtin_amdgcn_mfma_f32_16x16x32_f16(av, wh1[i], acc1, 0, 0, 0);
            }
            #pragma unroll
            for (int r = 0; r < 4; ++r) {
                red[kw][(lane >> 4)*4 + r][lane & 15]        = acc0[r];
                red[kw][(lane >> 4)*4 + r][16 + (lane & 15)] = acc1[r];
            }
            __syncthreads();
            if (threadIdx.x < 128) {
                const int nb = jl * 4;
                f32x4 base = (KIH > 0) ? bias4 : p4;
                float gi = base[0] + red[0][b][nb+0] + red[1][b][nb+0] + red[2][b][nb+0] + red[3][b][nb+0];
                float gf = base[1] + red[0][b][nb+1] + red[1][b][nb+1] + red[2][b][nb+1] + red[3][b][nb+1];
                float gg = base[2] + red[0][b][nb+2] + red[1][b][nb+2] + red[2][b][nb+2] + red[3][b][nb+2];
                float go = base[3] + red[0][b][nb+3] + red[1][b][nb+3] + red[2][b][nb+3] + red[3][b][nb+3];
                float c = sigm(gf) * cst[b][jl] + sigm(gi) * ftanh(gg);
                float h = sigm(go) * ftanh(c);
                cst[b][jl] = c;
                const int j = (n0 >> 2) + jl;
                hw[b*HpHH + j] = (f16)h;
                if constexpr (DELAY == 2) xs3[(size_t)(b*TT + t)*416 + j] = (f16)h;
                if (t == TT-1 && j < H) { hout[b*H + j] = h; cout[b*H + j] = c; }
                __builtin_amdgcn_fence(__ATOMIC_RELEASE, "agent");   // flush h to LLC
            }
        }
        if (s == NSTEPS-1) break;     // last compute is L3's; kernel-end flushes
        __syncthreads();
        if (threadIdx.x == 0)
            __hip_atomic_store(&arrive[blockIdx.x * 16], (unsigned)(s + 1),
                               __ATOMIC_RELAXED, __HIP_MEMORY_SCOPE_AGENT);
        for (int w = threadIdx.x; w < nwg; w += 256) {
            while (__hip_atomic_load(&arrive[w * 16], __ATOMIC_RELAXED,
                                     __HIP_MEMORY_SCOPE_AGENT) < (unsigned)(s + 1))
                __builtin_amdgcn_s_sleep(1);
        }
        __syncthreads();
        __builtin_amdgcn_fence(__ATOMIC_ACQUIRE, "agent");           // one inv per step
    }
}

__global__ __launch_bounds__(256, 2) void lstm_mega(
    const float* __restrict__ pre1,
    const float* __restrict__ bias2, const float* __restrict__ bias3,
    const f16* __restrict__ whh1,
    const f16* __restrict__ wih2, const f16* __restrict__ whh2,
    const f16* __restrict__ wih3, const f16* __restrict__ whh3,
    f16* h1A, f16* h1B, f16* h2A, f16* h2B, f16* h3A, f16* h3B,
    f16* xs3,
    float* h1o, float* c1o, float* h2o, float* c2o, float* h3o, float* c3o,
    unsigned* arrive)
{
    __shared__ float red[4][16][32];
    __shared__ float cst[16][8];
    const int bx = blockIdx.x;
    if (bx < NWG1) {
        lstm_role<0,9,0>(red, cst, pre1, nullptr, nullptr, whh1,
                         nullptr, nullptr, h1A, h1B, nullptr,
                         h1o, c1o, arrive, bx, HH);
    } else if (bx < NWG1 + NWG2) {
        lstm_role<9,9,1>(red, cst, nullptr, bias2, wih2, whh2,
                         h1A, h1B, h2A, h2B, nullptr,
                         h2o, c2o, arrive, bx - NWG1, HH);
    } else {
        lstm_role<9,4,2>(red, cst, nullptr, bias3, wih3, whh3,
                         h2A, h2B, h3A, h3B, xs3,
                         h3o, c3o, arrive, bx - NWG1 - NWG2, EE);
    }
}

// ---------------- host ----------------
extern "C" void kernel_launch(void* const* d_in, const int* in_sizes, int n_in,
                              void* d_out, int out_size, void* d_ws, size_t ws_size,
                              hipStream_t stream)
{
    const float* emb  = (const float*)d_in[0];
    const float* Wih1 = (const float*)d_in[1];
    const float* Whh1 = (const float*)d_in[2];
    const float* bih1 = (const float*)d_in[3];
    const float* bhh1 = (const float*)d_in[4];
    const float* Wih2 = (const float*)d_in[5];
    const float* Whh2 = (const float*)d_in[6];
    const float* bih2 = (const float*)d_in[7];
    const float* bhh2 = (const float*)d_in[8];
    const float* Wih3 = (const float*)d_in[9];
    const float* Whh3 = (const float*)d_in[10];
    const float* bih3 = (const float*)d_in[11];
    const float* bhh3 = (const float*)d_in[12];
    const float* linb = (const float*)d_in[13];
    const int*   x    = (const int*)d_in[14];
    float* out = (float*)d_out;
    char*  ws  = (char*)d_ws;
    char*  outc = (char*)d_out;

    // ---- ws layout (zeroed region first: flags + 6 h ping-pong buffers) ----
    const size_t ARR  = 0;                          // 340*64 = 21760 B
    const size_t H1A  = 21760;                      // 16*1152*2 = 36864 each
    const size_t H1B  = H1A + 36864;
    const size_t H2A  = H1B + 36864;
    const size_t H2B  = H2A + 36864;
    const size_t H3A  = H2B + 36864;                // 16*512*2 = 16384 each
    const size_t H3B  = H3A + 16384;
    const size_t ZEND = H3B + 16384;                // 201984 (256-aligned)
    size_t off = ZEND;
    auto alloc = [&](size_t bytes){ size_t r = off; off += (bytes + 255) & ~(size_t)255; return r; };
    const size_t EMBBF = alloc((size_t)VV*416*2);   // 26.6 MB
    const size_t XS0   = alloc((size_t)MM*416*2);   // embedded input, f16
    const size_t XS3   = alloc((size_t)MM*416*2);   // layer3 output, f16
    const size_t WIH1  = alloc((size_t)4608*416*2); // packed for pre-GEMM
    const size_t B1    = alloc((size_t)4608*4);
    const size_t B2    = alloc((size_t)4608*4);
    const size_t B3    = alloc((size_t)1664*4);

    f16* emb_bf = (f16*)(ws + EMBBF);
    f16* xs0    = (f16*)(ws + XS0);
    f16* xs3    = (f16*)(ws + XS3);
    f16* wih1p  = (f16*)(ws + WIH1);
    float* bias1 = (float*)(ws + B1);
    float* bias2 = (float*)(ws + B2);
    float* bias3 = (float*)(ws + B3);
    unsigned* arr = (unsigned*)(ws + ARR);

    // ---- big scratch lives in the (dead-until-final-GEMM) out buffer ----
    float* pre1 = out;                               // 2048*4608*4 = 37,748,736 B
    const size_t OW_HH1 = 37748736;                  // 4608*1152*2 = 10,616,832
    const size_t OW_IH2 = OW_HH1 + 10616832;
    const size_t OW_HH2 = OW_IH2 + 10616832;
    const size_t OW_IH3 = OW_HH2 + 10616832;         // 1664*1152*2 = 3,833,856
    const size_t OW_HH3 = OW_IH3 + 3833856;          // 1664*512*2  = 1,703,936
    f16* whh1p = (f16*)(outc + OW_HH1);
    f16* wih2p = (f16*)(outc + OW_IH2);
    f16* whh2p = (f16*)(outc + OW_HH2);
    f16* wih3p = (f16*)(outc + OW_IH3);
    f16* whh3p = (f16*)(outc + OW_HH3);

    float* H1O = out + 65536000;  float* H2O = H1O + 18400;  float* H3O = H2O + 18400;
    float* C1O = H3O + 6400;      float* C2O = C1O + 18400;  float* C3O = C2O + 18400;

    hipMemsetAsync(d_ws, 0, ZEND, stream);

    conv_emb    <<<dim3(2, VV), 256, 0, stream>>>(emb, emb_bf);
    embed_gather<<<dim3(2, MM), 256, 0, stream>>>(emb, x, xs0);

    // layer-1 input pre-GEMM (input known upfront; stays a throughput GEMM)
    conv_w   <<<dim3(2, 4608), 256, 0, stream>>>(Wih1, wih1p, HH, EE, 416);
    conv_bias<<<dim3(18),      256, 0, stream>>>(bih1, bhh1, bias1, HH, 4608);
    gemm16<0><<<dim3(36, 16),  256, 0, stream>>>(xs0, wih1p, bias1, pre1, 416, 4608);

    // pack all recurrent-phase weights/biases
    conv_w   <<<dim3(5, 4608), 256, 0, stream>>>(Whh1, whh1p, HH, HH, 1152);
    conv_w   <<<dim3(5, 4608), 256, 0, stream>>>(Wih2, wih2p, HH, HH, 1152);
    conv_w   <<<dim3(5, 4608), 256, 0, stream>>>(Whh2, whh2p, HH, HH, 1152);
    conv_w   <<<dim3(5, 1664), 256, 0, stream>>>(Wih3, wih3p, EE, HH, 1152);
    conv_w   <<<dim3(2, 1664), 256, 0, stream>>>(Whh3, whh3p, EE, EE, 512);
    conv_bias<<<dim3(18),      256, 0, stream>>>(bih2, bhh2, bias2, HH, 4608);
    conv_bias<<<dim3(7),       256, 0, stream>>>(bih3, bhh3, bias3, EE, 1664);

    // pipelined 3-layer recurrence: 130 global barrier steps instead of 384
    lstm_mega<<<dim3(NWG1 + NWG2 + NWG3), 256, 0, stream>>>(
        pre1, bias2, bias3, whh1p, wih2p, whh2p, wih3p, whh3p,
        (f16*)(ws+H1A), (f16*)(ws+H1B), (f16*)(ws+H2A), (f16*)(ws+H2B),
        (f16*)(ws+H3A), (f16*)(ws+H3B),
        xs3, H1O, C1O, H2O, C2O, H3O, C3O, arr);

    // tied-weight logits with fused transpose to (B,V,T)
    gemm16<1><<<dim3(250, 16), 256, 0, stream>>>(xs3, emb_bf, linb, out, 416, 0);
}

// Round 3
// 1335.683 us; speedup vs baseline: 3.4136x; 3.1264x over previous
//
#include <hip/hip_runtime.h>

typedef _Float16 f16;
typedef _Float16 f16x8 __attribute__((ext_vector_type(8)));
typedef float f32x4 __attribute__((ext_vector_type(4)));

// dims
#define BB 16
#define TT 128
#define VV 32000
#define EE 400
#define HH 1150
#define MM 2048   // T*B rows

#define NWG1 144          // layer1 blocks (4608/32)
#define NWG2 144          // layer2 blocks
#define NWG3 52           // layer3 blocks (1664/32)
#define NSTEPS 130        // 128 + 2 pipeline-fill steps

__device__ __forceinline__ float sigm(float x){ return 1.f/(1.f + __expf(-x)); }
__device__ __forceinline__ float ftanh(float x){ return 2.f/(1.f + __expf(-2.f*x)) - 1.f; }

// Device-coherent (cross-XCD) access for the h-exchange ONLY: sc0+sc1 bypass
// the per-XCD L2, so we never need the per-step agent acquire fence whose
// buffer_inv was wiping the weight working set out of L2 every step.
__device__ __forceinline__ void ld16c(f16x8& d, const f16* p){
    asm volatile("global_load_dwordx4 %0, %1, off sc0 sc1"
                 : "=v"(d) : "v"(p) : "memory");
}
__device__ __forceinline__ void st2c(f16* p, f16 v){
    asm volatile("global_store_short %0, %1, off sc0 sc1"
                 :: "v"(p), "v"(v) : "memory");
}

// ---------------- conversion kernels ----------------

__global__ void conv_emb(const float* __restrict__ src, f16* __restrict__ dst){
    int v = blockIdx.y;
    int k = blockIdx.x*256 + threadIdx.x;
    if (k >= 416) return;
    float val = (k < EE) ? src[v*EE + k] : 0.f;
    dst[v*416 + k] = (f16)val;
}

__global__ void embed_gather(const float* __restrict__ emb, const int* __restrict__ x,
                             f16* __restrict__ dst){
    int m = blockIdx.y;            // t*16+b
    int k = blockIdx.x*256 + threadIdx.x;
    if (k >= 416) return;
    int t = m >> 4, b = m & 15;
    int row = x[b*TT + t];
    float val = (k < EE) ? emb[row*EE + k] : 0.f;
    dst[m*416 + k] = (f16)val;
}

// W (4*Hout, Ksrc) f32 -> dst (Np, Kp) f16, dst row n = j*4+g  <- src row g*Hout+j
__global__ void conv_w(const float* __restrict__ src, f16* __restrict__ dst,
                       int Hout, int Ksrc, int Kp){
    int n = blockIdx.y;
    int k = blockIdx.x*256 + threadIdx.x;
    if (k >= Kp) return;
    int j = n >> 2, g = n & 3;
    float val = (j < Hout && k < Ksrc) ? src[(g*Hout + j)*Ksrc + k] : 0.f;
    dst[(size_t)n*Kp + k] = (f16)val;
}

__global__ void conv_bias(const float* __restrict__ bi, const float* __restrict__ bh,
                          float* __restrict__ dst, int Hout, int Np){
    int n = blockIdx.x*256 + threadIdx.x;
    if (n >= Np) return;
    int j = n >> 2, g = n & 3;
    dst[n] = (j < Hout) ? (bi[g*Hout + j] + bh[g*Hout + j]) : 0.f;
}

// ---------------- GEMM: C(M,N) = A(M,Kp) * B(N,Kp)^T + bias ----------------
template<int SC>
__global__ __launch_bounds__(256) void gemm16(
    const f16* __restrict__ A, const f16* __restrict__ B,
    const float* __restrict__ bias, float* __restrict__ C,
    int Kp, int Nst)
{
    __shared__ __align__(16) f16 lA[128*32];
    __shared__ __align__(16) f16 lB[128*32];
    const int lane = threadIdx.x & 63;
    const int wid  = threadIdx.x >> 6;
    const int m0 = blockIdx.y * 128, n0 = blockIdx.x * 128;
    f32x4 acc[4][4] = {};
    const int sr = threadIdx.x >> 2;
    const int sc = (threadIdx.x & 3) * 8;
    for (int k0 = 0; k0 < Kp; k0 += 32) {
        __syncthreads();
        *(f16x8*)&lA[ sr      *32 + sc] = *(const f16x8*)&A[(size_t)(m0 + sr     )*Kp + k0 + sc];
        *(f16x8*)&lA[(sr + 64)*32 + sc] = *(const f16x8*)&A[(size_t)(m0 + sr + 64)*Kp + k0 + sc];
        *(f16x8*)&lB[ sr      *32 + sc] = *(const f16x8*)&B[(size_t)(n0 + sr     )*Kp + k0 + sc];
        *(f16x8*)&lB[(sr + 64)*32 + sc] = *(const f16x8*)&B[(size_t)(n0 + sr + 64)*Kp + k0 + sc];
        __syncthreads();
        const int wr = (wid >> 1) * 64, wc = (wid & 1) * 64;
        f16x8 af[4], bf[4];
        #pragma unroll
        for (int i = 0; i < 4; ++i)
            af[i] = *(const f16x8*)&lA[(wr + i*16 + (lane & 15))*32 + (lane >> 4)*8];
        #pragma unroll
        for (int j = 0; j < 4; ++j)
            bf[j] = *(const f16x8*)&lB[(wc + j*16 + (lane & 15))*32 + (lane >> 4)*8];
        #pragma unroll
        for (int i = 0; i < 4; ++i)
            #pragma unroll
            for (int j = 0; j < 4; ++j)
                acc[i][j] = __builtin_amdgcn_mfma_f32_16x16x32_f16(af[i], bf[j], acc[i][j], 0, 0, 0);
    }
    const int wr = (wid >> 1) * 64, wc = (wid & 1) * 64;
    #pragma unroll
    for (int i = 0; i < 4; ++i) {
        #pragma unroll
        for (int j = 0; j < 4; ++j) {
            int gc = n0 + wc + j*16 + (lane & 15);
            float bb = bias[gc];
            #pragma unroll
            for (int r = 0; r < 4; ++r) {
                int gr = m0 + wr + i*16 + (lane >> 4)*4 + r;
                float v = acc[i][j][r] + bb;
                if (SC) C[((size_t)(gr >> 7)*VV + gc)*TT + (gr & 127)] = v;   // out[b][v][t]
                else    C[(size_t)gr*Nst + gc] = v;
            }
        }
    }
}

// ---------------- pipelined persistent 3-layer LSTM ----------------
// Global step s: layer1 does t=s, layer2 t=s-1, layer3 t=s-2; one global
// spin-barrier per step (130 instead of 384 sequential barriers).
// NO agent fences in the loop: the h ping-pong exchange uses sc0|sc1
// (L2-bypass, LLC-coherent) loads/stores + per-wave vmcnt(0) before the
// arrive-flag store. Weights/pre/bias use normal cached loads and stay
// L2-resident across all steps (round-2 bottleneck: per-step buffer_inv
// forced a 37 MB/step LLC re-stream -> 28 us/step).

template<int KIH, int KHH, int DELAY>
__device__ __forceinline__ void lstm_role(
    float (&red)[4][16][32], float (&cst)[16][8],
    const float* __restrict__ pre,     // L1 only (KIH==0): (2048,4608) rows t*16+b, bias folded in
    const float* __restrict__ bias,    // L2/L3: packed (Np)
    const f16* __restrict__ Wih,       // (Np,1152) packed, KIH>0 only
    const f16* __restrict__ Whh,       // (Np,HpHH) packed
    const f16* __restrict__ xA, const f16* __restrict__ xB,  // producer h ping-pong
    f16* __restrict__ hA, f16* __restrict__ hB,              // own h ping-pong
    f16* __restrict__ xs3,             // L3 only: (b*TT+t)*416+j
    float* __restrict__ hout, float* __restrict__ cout,
    unsigned* __restrict__ arrive, int bid, int H)
{
    constexpr int HpHH = KHH * 128;
    constexpr int KIHA = (KIH > 0) ? KIH : 1;
    const int lane = threadIdx.x & 63, kw = threadIdx.x >> 6;
    const int n0 = bid * 32;
    const int nwg = gridDim.x;
    if (threadIdx.x < 128) cst[threadIdx.x & 15][threadIdx.x >> 4] = 0.f;
    const int arow = lane & 15, aoff = (lane >> 4) * 8;
    const size_t hofsHH = (size_t)arow * HpHH + kw * (KHH * 32) + aoff;
    const size_t hofsIH = (size_t)arow * 1152 + kw * 288 + aoff;

    // weight slice base pointers (normal cached loads; L2 stays warm now
    // that nothing invalidates it -- compiler free to hoist into regs)
    const f16* wph0 = Whh + (size_t)(n0 + arow) * HpHH + kw * (KHH * 32) + aoff;
    const f16* wph1 = wph0 + (size_t)16 * HpHH;
    const f16* wpi0 = (KIH > 0) ? (Wih + (size_t)(n0 + arow) * 1152 + kw * 288 + aoff) : nullptr;
    const f16* wpi1 = (KIH > 0) ? (wpi0 + (size_t)16 * 1152) : nullptr;
    f16x8 wh0[KHH], wh1[KHH];
    #pragma unroll
    for (int i = 0; i < KHH; ++i) {
        wh0[i] = *(const f16x8*)(wph0 + i*32);
        wh1[i] = *(const f16x8*)(wph1 + i*32);
    }
    f16x8 wi0[KIHA], wi1[KIHA];
    if constexpr (KIH > 0) {
        #pragma unroll
        for (int i = 0; i < KIH; ++i) {
            wi0[i] = *(const f16x8*)(wpi0 + i*32);
            wi1[i] = *(const f16x8*)(wpi1 + i*32);
        }
    }
    const int b  = threadIdx.x & 15;
    const int jl = threadIdx.x >> 4;      // 0..7 when tid<128
    f32x4 bias4 = {0.f,0.f,0.f,0.f};
    if constexpr (KIH > 0) {
        if (threadIdx.x < 128) bias4 = *(const f32x4*)(bias + n0 + jl*4);
    }
    __syncthreads();

    for (int s = 0; s < NSTEPS; ++s) {
        const int t = s - DELAY;
        if (t >= 0 && t < TT) {
            const f16* hp = ((t & 1) ? hB : hA) + hofsHH;
            f16* hw       =  (t & 1) ? hA : hB;
            f32x4 p4;
            if constexpr (KIH == 0) {
                if (threadIdx.x < 128)
                    p4 = *(const f32x4*)(pre + (size_t)(t*16 + b)*4608 + n0 + jl*4);
            }
            // issue all coherent h loads, then one wait
            f16x8 xv[KIHA], hv[KHH];
            if constexpr (KIH > 0) {
                const f16* xp = ((t & 1) ? xA : xB) + hofsIH;   // producer h_t
                #pragma unroll
                for (int i = 0; i < KIH; ++i) ld16c(xv[i], xp + i*32);
            }
            #pragma unroll
            for (int i = 0; i < KHH; ++i) ld16c(hv[i], hp + i*32);
            asm volatile("s_waitcnt vmcnt(0)" ::: "memory");
            __builtin_amdgcn_sched_barrier(0);

            f32x4 acc0 = {0.f,0.f,0.f,0.f}, acc1 = {0.f,0.f,0.f,0.f};
            if constexpr (KIH > 0) {
                #pragma unroll
                for (int i = 0; i < KIH; ++i) {
                    acc0 = __builtin_amdgcn_mfma_f32_16x16x32_f16(xv[i], wi0[i], acc0, 0, 0, 0);
                    acc1 = __builtin_amdgcn_mfma_f32_16x16x32_f16(xv[i], wi1[i], acc1, 0, 0, 0);
                }
            }
            #pragma unroll
            for (int i = 0; i < KHH; ++i) {
                acc0 = __builtin_amdgcn_mfma_f32_16x16x32_f16(hv[i], wh0[i], acc0, 0, 0, 0);
                acc1 = __builtin_amdgcn_mfma_f32_16x16x32_f16(hv[i], wh1[i], acc1, 0, 0, 0);
            }
            #pragma unroll
            for (int r = 0; r < 4; ++r) {
                red[kw][(lane >> 4)*4 + r][lane & 15]        = acc0[r];
                red[kw][(lane >> 4)*4 + r][16 + (lane & 15)] = acc1[r];
            }
            __syncthreads();
            if (threadIdx.x < 128) {
                const int nb = jl * 4;
                f32x4 base = (KIH > 0) ? bias4 : p4;
                float gi = base[0] + red[0][b][nb+0] + red[1][b][nb+0] + red[2][b][nb+0] + red[3][b][nb+0];
                float gf = base[1] + red[0][b][nb+1] + red[1][b][nb+1] + red[2][b][nb+1] + red[3][b][nb+1];
                float gg = base[2] + red[0][b][nb+2] + red[1][b][nb+2] + red[2][b][nb+2] + red[3][b][nb+2];
                float go = base[3] + red[0][b][nb+3] + red[1][b][nb+3] + red[2][b][nb+3] + red[3][b][nb+3];
                float c = sigm(gf) * cst[b][jl] + sigm(gi) * ftanh(gg);
                float h = sigm(go) * ftanh(c);
                cst[b][jl] = c;
                const int j = (n0 >> 2) + jl;
                st2c(hw + b*HpHH + j, (f16)h);                       // coherent h store
                if constexpr (DELAY == 2) xs3[(size_t)(b*TT + t)*416 + j] = (f16)h;
                if (t == TT-1 && j < H) { hout[b*H + j] = h; cout[b*H + j] = c; }
                asm volatile("s_waitcnt vmcnt(0)" ::: "memory");     // h at LLC before flag
            }
        }
        if (s == NSTEPS-1) break;     // last compute is L3's; kernel-end flushes
        __syncthreads();
        if (threadIdx.x == 0)
            __hip_atomic_store(&arrive[blockIdx.x * 16], (unsigned)(s + 1),
                               __ATOMIC_RELAXED, __HIP_MEMORY_SCOPE_AGENT);
        for (int w = threadIdx.x; w < nwg; w += 256) {
            while (__hip_atomic_load(&arrive[w * 16], __ATOMIC_RELAXED,
                                     __HIP_MEMORY_SCOPE_AGENT) < (unsigned)(s + 1))
                __builtin_amdgcn_s_sleep(1);
        }
        __syncthreads();
        // no acquire fence: h reads are sc1 (LLC-coherent) by construction
    }
}

__global__ __launch_bounds__(256, 2) void lstm_mega(
    const float* __restrict__ pre1,
    const float* __restrict__ bias2, const float* __restrict__ bias3,
    const f16* __restrict__ whh1,
    const f16* __restrict__ wih2, const f16* __restrict__ whh2,
    const f16* __restrict__ wih3, const f16* __restrict__ whh3,
    f16* h1A, f16* h1B, f16* h2A, f16* h2B, f16* h3A, f16* h3B,
    f16* xs3,
    float* h1o, float* c1o, float* h2o, float* c2o, float* h3o, float* c3o,
    unsigned* arrive)
{
    __shared__ float red[4][16][32];
    __shared__ float cst[16][8];
    const int bx = blockIdx.x;
    if (bx < NWG1) {
        lstm_role<0,9,0>(red, cst, pre1, nullptr, nullptr, whh1,
                         nullptr, nullptr, h1A, h1B, nullptr,
                         h1o, c1o, arrive, bx, HH);
    } else if (bx < NWG1 + NWG2) {
        lstm_role<9,9,1>(red, cst, nullptr, bias2, wih2, whh2,
                         h1A, h1B, h2A, h2B, nullptr,
                         h2o, c2o, arrive, bx - NWG1, HH);
    } else {
        lstm_role<9,4,2>(red, cst, nullptr, bias3, wih3, whh3,
                         h2A, h2B, h3A, h3B, xs3,
                         h3o, c3o, arrive, bx - NWG1 - NWG2, EE);
    }
}

// ---------------- host ----------------
extern "C" void kernel_launch(void* const* d_in, const int* in_sizes, int n_in,
                              void* d_out, int out_size, void* d_ws, size_t ws_size,
                              hipStream_t stream)
{
    const float* emb  = (const float*)d_in[0];
    const float* Wih1 = (const float*)d_in[1];
    const float* Whh1 = (const float*)d_in[2];
    const float* bih1 = (const float*)d_in[3];
    const float* bhh1 = (const float*)d_in[4];
    const float* Wih2 = (const float*)d_in[5];
    const float* Whh2 = (const float*)d_in[6];
    const float* bih2 = (const float*)d_in[7];
    const float* bhh2 = (const float*)d_in[8];
    const float* Wih3 = (const float*)d_in[9];
    const float* Whh3 = (const float*)d_in[10];
    const float* bih3 = (const float*)d_in[11];
    const float* bhh3 = (const float*)d_in[12];
    const float* linb = (const float*)d_in[13];
    const int*   x    = (const int*)d_in[14];
    float* out = (float*)d_out;
    char*  ws  = (char*)d_ws;
    char*  outc = (char*)d_out;

    // ---- ws layout (zeroed region first: flags + 6 h ping-pong buffers) ----
    const size_t ARR  = 0;                          // 340*64 = 21760 B
    const size_t H1A  = 21760;                      // 16*1152*2 = 36864 each
    const size_t H1B  = H1A + 36864;
    const size_t H2A  = H1B + 36864;
    const size_t H2B  = H2A + 36864;
    const size_t H3A  = H2B + 36864;                // 16*512*2 = 16384 each
    const size_t H3B  = H3A + 16384;
    const size_t ZEND = H3B + 16384;                // 201984 (256-aligned)
    size_t off = ZEND;
    auto alloc = [&](size_t bytes){ size_t r = off; off += (bytes + 255) & ~(size_t)255; return r; };
    const size_t EMBBF = alloc((size_t)VV*416*2);   // 26.6 MB
    const size_t XS0   = alloc((size_t)MM*416*2);   // embedded input, f16
    const size_t XS3   = alloc((size_t)MM*416*2);   // layer3 output, f16
    const size_t WIH1  = alloc((size_t)4608*416*2); // packed for pre-GEMM
    const size_t B1    = alloc((size_t)4608*4);
    const size_t B2    = alloc((size_t)4608*4);
    const size_t B3    = alloc((size_t)1664*4);

    f16* emb_bf = (f16*)(ws + EMBBF);
    f16* xs0    = (f16*)(ws + XS0);
    f16* xs3    = (f16*)(ws + XS3);
    f16* wih1p  = (f16*)(ws + WIH1);
    float* bias1 = (float*)(ws + B1);
    float* bias2 = (float*)(ws + B2);
    float* bias3 = (float*)(ws + B3);
    unsigned* arr = (unsigned*)(ws + ARR);

    // ---- big scratch lives in the (dead-until-final-GEMM) out buffer ----
    float* pre1 = out;                               // 2048*4608*4 = 37,748,736 B
    const size_t OW_HH1 = 37748736;                  // 4608*1152*2 = 10,616,832
    const size_t OW_IH2 = OW_HH1 + 10616832;
    const size_t OW_HH2 = OW_IH2 + 10616832;
    const size_t OW_IH3 = OW_HH2 + 10616832;         // 1664*1152*2 = 3,833,856
    const size_t OW_HH3 = OW_IH3 + 3833856;          // 1664*512*2  = 1,703,936
    f16* whh1p = (f16*)(outc + OW_HH1);
    f16* wih2p = (f16*)(outc + OW_IH2);
    f16* whh2p = (f16*)(outc + OW_HH2);
    f16* wih3p = (f16*)(outc + OW_IH3);
    f16* whh3p = (f16*)(outc + OW_HH3);

    float* H1O = out + 65536000;  float* H2O = H1O + 18400;  float* H3O = H2O + 18400;
    float* C1O = H3O + 6400;      float* C2O = C1O + 18400;  float* C3O = C2O + 18400;

    hipMemsetAsync(d_ws, 0, ZEND, stream);

    conv_emb    <<<dim3(2, VV), 256, 0, stream>>>(emb, emb_bf);
    embed_gather<<<dim3(2, MM), 256, 0, stream>>>(emb, x, xs0);

    // layer-1 input pre-GEMM (input known upfront; stays a throughput GEMM)
    conv_w   <<<dim3(2, 4608), 256, 0, stream>>>(Wih1, wih1p, HH, EE, 416);
    conv_bias<<<dim3(18),      256, 0, stream>>>(bih1, bhh1, bias1, HH, 4608);
    gemm16<0><<<dim3(36, 16),  256, 0, stream>>>(xs0, wih1p, bias1, pre1, 416, 4608);

    // pack all recurrent-phase weights/biases
    conv_w   <<<dim3(5, 4608), 256, 0, stream>>>(Whh1, whh1p, HH, HH, 1152);
    conv_w   <<<dim3(5, 4608), 256, 0, stream>>>(Wih2, wih2p, HH, HH, 1152);
    conv_w   <<<dim3(5, 4608), 256, 0, stream>>>(Whh2, whh2p, HH, HH, 1152);
    conv_w   <<<dim3(5, 1664), 256, 0, stream>>>(Wih3, wih3p, EE, HH, 1152);
    conv_w   <<<dim3(2, 1664), 256, 0, stream>>>(Whh3, whh3p, EE, EE, 512);
    conv_bias<<<dim3(18),      256, 0, stream>>>(bih2, bhh2, bias2, HH, 4608);
    conv_bias<<<dim3(7),       256, 0, stream>>>(bih3, bhh3, bias3, EE, 1664);

    // pipelined 3-layer recurrence: 130 global barrier steps, no L2 invalidates
    lstm_mega<<<dim3(NWG1 + NWG2 + NWG3), 256, 0, stream>>>(
        pre1, bias2, bias3, whh1p, wih2p, whh2p, wih3p, whh3p,
        (f16*)(ws+H1A), (f16*)(ws+H1B), (f16*)(ws+H2A), (f16*)(ws+H2B),
        (f16*)(ws+H3A), (f16*)(ws+H3B),
        xs3, H1O, C1O, H2O, C2O, H3O, C3O, arr);

    // tied-weight logits with fused transpose to (B,V,T)
    gemm16<1><<<dim3(250, 16), 256, 0, stream>>>(xs3, emb_bf, linb, out, 416, 0);
}

// Round 4
// 1195.548 us; speedup vs baseline: 3.8137x; 1.1172x over previous
//
#include <hip/hip_runtime.h>

typedef _Float16 f16;
typedef _Float16 f16x8 __attribute__((ext_vector_type(8)));
typedef float f32x4 __attribute__((ext_vector_type(4)));

// dims
#define BB 16
#define TT 128
#define VV 32000
#define EE 400
#define HH 1150
#define MM 2048   // T*B rows

#define NWG1 72           // layer1 blocks (4608/64)
#define NWG2 144          // layer2 blocks (4608/32)
#define NWG3 26           // layer3 blocks (1664/64)
#define NWGT (NWG1+NWG2+NWG3)   // 242 <= 256 CUs -> 1 block/CU
#define NSTEPS 130        // 128 + 2 pipeline-fill steps

__device__ __forceinline__ float sigm(float x){ return 1.f/(1.f + __expf(-x)); }
__device__ __forceinline__ float ftanh(float x){ return 2.f/(1.f + __expf(-2.f*x)) - 1.f; }

// Device-coherent (cross-XCD) access for the h-exchange ONLY: sc0+sc1 bypass
// the per-XCD L2, so no per-step acquire fence (whose buffer_inv would wipe
// the L2-resident weights -> round-2's 28 us/step regression).
__device__ __forceinline__ void ld16c(f16x8& d, const f16* p){
    asm volatile("global_load_dwordx4 %0, %1, off sc0 sc1"
                 : "=v"(d) : "v"(p) : "memory");
}
__device__ __forceinline__ void st2c(f16* p, f16 v){
    asm volatile("global_store_short %0, %1, off sc0 sc1"
                 :: "v"(p), "v"(v) : "memory");
}

// ---------------- conversion kernels ----------------

__global__ void conv_emb(const float* __restrict__ src, f16* __restrict__ dst){
    int v = blockIdx.y;
    int k = blockIdx.x*256 + threadIdx.x;
    if (k >= 416) return;
    float val = (k < EE) ? src[v*EE + k] : 0.f;
    dst[v*416 + k] = (f16)val;
}

__global__ void embed_gather(const float* __restrict__ emb, const int* __restrict__ x,
                             f16* __restrict__ dst){
    int m = blockIdx.y;            // t*16+b
    int k = blockIdx.x*256 + threadIdx.x;
    if (k >= 416) return;
    int t = m >> 4, b = m & 15;
    int row = x[b*TT + t];
    float val = (k < EE) ? emb[row*EE + k] : 0.f;
    dst[m*416 + k] = (f16)val;
}

// W (4*Hout, Ksrc) f32 -> dst (Np, Kp) f16, dst row n = j*4+g  <- src row g*Hout+j
__global__ void conv_w(const float* __restrict__ src, f16* __restrict__ dst,
                       int Hout, int Ksrc, int Kp){
    int n = blockIdx.y;
    int k = blockIdx.x*256 + threadIdx.x;
    if (k >= Kp) return;
    int j = n >> 2, g = n & 3;
    float val = (j < Hout && k < Ksrc) ? src[(g*Hout + j)*Ksrc + k] : 0.f;
    dst[(size_t)n*Kp + k] = (f16)val;
}

__global__ void conv_bias(const float* __restrict__ bi, const float* __restrict__ bh,
                          float* __restrict__ dst, int Hout, int Np){
    int n = blockIdx.x*256 + threadIdx.x;
    if (n >= Np) return;
    int j = n >> 2, g = n & 3;
    dst[n] = (j < Hout) ? (bi[g*Hout + j] + bh[g*Hout + j]) : 0.f;
}

// ---------------- GEMM: C(M,N) = A(M,Kp) * B(N,Kp)^T + bias ----------------
template<int SC>
__global__ __launch_bounds__(256) void gemm16(
    const f16* __restrict__ A, const f16* __restrict__ B,
    const float* __restrict__ bias, float* __restrict__ C,
    int Kp, int Nst)
{
    __shared__ __align__(16) f16 lA[128*32];
    __shared__ __align__(16) f16 lB[128*32];
    const int lane = threadIdx.x & 63;
    const int wid  = threadIdx.x >> 6;
    const int m0 = blockIdx.y * 128, n0 = blockIdx.x * 128;
    f32x4 acc[4][4] = {};
    const int sr = threadIdx.x >> 2;
    const int sc = (threadIdx.x & 3) * 8;
    for (int k0 = 0; k0 < Kp; k0 += 32) {
        __syncthreads();
        *(f16x8*)&lA[ sr      *32 + sc] = *(const f16x8*)&A[(size_t)(m0 + sr     )*Kp + k0 + sc];
        *(f16x8*)&lA[(sr + 64)*32 + sc] = *(const f16x8*)&A[(size_t)(m0 + sr + 64)*Kp + k0 + sc];
        *(f16x8*)&lB[ sr      *32 + sc] = *(const f16x8*)&B[(size_t)(n0 + sr     )*Kp + k0 + sc];
        *(f16x8*)&lB[(sr + 64)*32 + sc] = *(const f16x8*)&B[(size_t)(n0 + sr + 64)*Kp + k0 + sc];
        __syncthreads();
        const int wr = (wid >> 1) * 64, wc = (wid & 1) * 64;
        f16x8 af[4], bf[4];
        #pragma unroll
        for (int i = 0; i < 4; ++i)
            af[i] = *(const f16x8*)&lA[(wr + i*16 + (lane & 15))*32 + (lane >> 4)*8];
        #pragma unroll
        for (int j = 0; j < 4; ++j)
            bf[j] = *(const f16x8*)&lB[(wc + j*16 + (lane & 15))*32 + (lane >> 4)*8];
        #pragma unroll
        for (int i = 0; i < 4; ++i)
            #pragma unroll
            for (int j = 0; j < 4; ++j)
                acc[i][j] = __builtin_amdgcn_mfma_f32_16x16x32_f16(af[i], bf[j], acc[i][j], 0, 0, 0);
    }
    const int wr = (wid >> 1) * 64, wc = (wid & 1) * 64;
    #pragma unroll
    for (int i = 0; i < 4; ++i) {
        #pragma unroll
        for (int j = 0; j < 4; ++j) {
            int gc = n0 + wc + j*16 + (lane & 15);
            float bb = bias[gc];
            #pragma unroll
            for (int r = 0; r < 4; ++r) {
                int gr = m0 + wr + i*16 + (lane >> 4)*4 + r;
                float v = acc[i][j][r] + bb;
                if (SC) C[((size_t)(gr >> 7)*VV + gc)*TT + (gr & 127)] = v;   // out[b][v][t]
                else    C[(size_t)gr*Nst + gc] = v;
            }
        }
    }
}

// ---------------- pipelined persistent 3-layer LSTM ----------------
// Global step s: layer1 t=s, layer2 t=s-1, layer3 t=s-2; one global
// spin-barrier per step. 242 blocks, 1 per CU (round-3 had 340 blocks at
// 2/CU: CUs hosting two L2-role blocks did 2x work and paced the barrier
// every step). NG = number of 16-gate groups per block (G = NG*16 gates).

template<int KIH, int KHH, int DELAY, int NG>
__device__ __forceinline__ void lstm_role(
    float (&red)[4][16][66], float (&cst)[16][16],
    const float* __restrict__ pre,     // L1 only (KIH==0): (2048,4608) rows t*16+b, bias folded in
    const float* __restrict__ bias,    // L2/L3: packed (Np)
    const f16* __restrict__ Wih,       // (Np,1152) packed, KIH>0 only
    const f16* __restrict__ Whh,       // (Np,HpHH) packed
    const f16* __restrict__ xA, const f16* __restrict__ xB,  // producer h ping-pong
    f16* __restrict__ hA, f16* __restrict__ hB,              // own h ping-pong
    f16* __restrict__ xs3,             // L3 only: (b*TT+t)*416+j
    float* __restrict__ hout, float* __restrict__ cout,
    unsigned* __restrict__ arrive, int bid, int H)
{
    constexpr int HpHH = KHH * 128;
    constexpr int KIHA = (KIH > 0) ? KIH : 1;
    constexpr int G = NG * 16;
    const int lane = threadIdx.x & 63, kw = threadIdx.x >> 6;
    const int n0 = bid * G;
    const int nwg = gridDim.x;
    cst[threadIdx.x & 15][threadIdx.x >> 4] = 0.f;   // 256 threads cover 16x16
    const int arow = lane & 15, aoff = (lane >> 4) * 8;
    const size_t hofsHH = (size_t)arow * HpHH + kw * (KHH * 32) + aoff;
    const size_t hofsIH = (size_t)arow * 1152 + kw * 288 + aoff;

    // weight slices, register-resident (normal cached loads; L2 stays warm)
    f16x8 wh[NG][KHH];
    #pragma unroll
    for (int g = 0; g < NG; ++g) {
        const f16* wp = Whh + (size_t)(n0 + g*16 + arow) * HpHH + kw * (KHH*32) + aoff;
        #pragma unroll
        for (int i = 0; i < KHH; ++i) wh[g][i] = *(const f16x8*)(wp + i*32);
    }
    f16x8 wi[NG][KIHA];
    if constexpr (KIH > 0) {
        #pragma unroll
        for (int g = 0; g < NG; ++g) {
            const f16* wp = Wih + (size_t)(n0 + g*16 + arow) * 1152 + kw * 288 + aoff;
            #pragma unroll
            for (int i = 0; i < KIH; ++i) wi[g][i] = *(const f16x8*)(wp + i*32);
        }
    }
    const int b  = threadIdx.x & 15;
    const int jl = threadIdx.x >> 4;      // 0..(NG*4-1) in the update guard
    f32x4 bias4 = {0.f,0.f,0.f,0.f};
    if constexpr (KIH > 0) {
        if (threadIdx.x < NG*64) bias4 = *(const f32x4*)(bias + n0 + jl*4);
    }
    __syncthreads();

    for (int s = 0; s < NSTEPS; ++s) {
        const int t = s - DELAY;
        if (t >= 0 && t < TT) {
            const f16* hp = ((t & 1) ? hB : hA) + hofsHH;
            f16* hw       =  (t & 1) ? hA : hB;
            f32x4 p4;
            if constexpr (KIH == 0) {
                if (threadIdx.x < NG*64)
                    p4 = *(const f32x4*)(pre + (size_t)(t*16 + b)*4608 + n0 + jl*4);
            }
            // issue all coherent h loads, then one wait
            f16x8 xv[KIHA], hv[KHH];
            if constexpr (KIH > 0) {
                const f16* xp = ((t & 1) ? xA : xB) + hofsIH;   // producer h_t
                #pragma unroll
                for (int i = 0; i < KIH; ++i) ld16c(xv[i], xp + i*32);
            }
            #pragma unroll
            for (int i = 0; i < KHH; ++i) ld16c(hv[i], hp + i*32);
            asm volatile("s_waitcnt vmcnt(0)" ::: "memory");
            __builtin_amdgcn_sched_barrier(0);

            f32x4 acc[NG] = {};
            if constexpr (KIH > 0) {
                #pragma unroll
                for (int i = 0; i < KIH; ++i)
                    #pragma unroll
                    for (int g = 0; g < NG; ++g)
                        acc[g] = __builtin_amdgcn_mfma_f32_16x16x32_f16(xv[i], wi[g][i], acc[g], 0, 0, 0);
            }
            #pragma unroll
            for (int i = 0; i < KHH; ++i)
                #pragma unroll
                for (int g = 0; g < NG; ++g)
                    acc[g] = __builtin_amdgcn_mfma_f32_16x16x32_f16(hv[i], wh[g][i], acc[g], 0, 0, 0);

            #pragma unroll
            for (int g = 0; g < NG; ++g)
                #pragma unroll
                for (int r = 0; r < 4; ++r)
                    red[kw][(lane >> 4)*4 + r][g*16 + (lane & 15)] = acc[g][r];
            __syncthreads();
            if (threadIdx.x < NG*64) {
                const int nb = jl * 4;
                f32x4 base = (KIH > 0) ? bias4 : p4;
                float gi = base[0] + red[0][b][nb+0] + red[1][b][nb+0] + red[2][b][nb+0] + red[3][b][nb+0];
                float gf = base[1] + red[0][b][nb+1] + red[1][b][nb+1] + red[2][b][nb+1] + red[3][b][nb+1];
                float gg = base[2] + red[0][b][nb+2] + red[1][b][nb+2] + red[2][b][nb+2] + red[3][b][nb+2];
                float go = base[3] + red[0][b][nb+3] + red[1][b][nb+3] + red[2][b][nb+3] + red[3][b][nb+3];
                float c = sigm(gf) * cst[b][jl] + sigm(gi) * ftanh(gg);
                float h = sigm(go) * ftanh(c);
                cst[b][jl] = c;
                const int j = (n0 >> 2) + jl;
                st2c(hw + b*HpHH + j, (f16)h);                       // coherent h store
                if constexpr (DELAY == 2) xs3[(size_t)(b*TT + t)*416 + j] = (f16)h;
                if (t == TT-1 && j < H) { hout[b*H + j] = h; cout[b*H + j] = c; }
                asm volatile("s_waitcnt vmcnt(0)" ::: "memory");     // h at LLC before flag
            }
        }
        if (s == NSTEPS-1) break;     // last compute is L3's; kernel-end flushes
        __syncthreads();
        if (threadIdx.x == 0)
            __hip_atomic_store(&arrive[blockIdx.x * 16], (unsigned)(s + 1),
                               __ATOMIC_RELAXED, __HIP_MEMORY_SCOPE_AGENT);
        for (int w = threadIdx.x; w < nwg; w += 256) {
            while (__hip_atomic_load(&arrive[w * 16], __ATOMIC_RELAXED,
                                     __HIP_MEMORY_SCOPE_AGENT) < (unsigned)(s + 1))
                __builtin_amdgcn_s_sleep(1);
        }
        __syncthreads();
        // no acquire fence: h reads are sc1 (LLC-coherent) by construction
    }
}

__global__ __launch_bounds__(256, 1) void lstm_mega(
    const float* __restrict__ pre1,
    const float* __restrict__ bias2, const float* __restrict__ bias3,
    const f16* __restrict__ whh1,
    const f16* __restrict__ wih2, const f16* __restrict__ whh2,
    const f16* __restrict__ wih3, const f16* __restrict__ whh3,
    f16* h1A, f16* h1B, f16* h2A, f16* h2B, f16* h3A, f16* h3B,
    f16* xs3,
    float* h1o, float* c1o, float* h2o, float* c2o, float* h3o, float* c3o,
    unsigned* arrive)
{
    __shared__ float red[4][16][66];   // stride 66: breaks 4-way write / 16-way read bank aliasing
    __shared__ float cst[16][16];
    const int bx = blockIdx.x;
    if (bx < NWG1) {
        lstm_role<0,9,0,4>(red, cst, pre1, nullptr, nullptr, whh1,
                           nullptr, nullptr, h1A, h1B, nullptr,
                           h1o, c1o, arrive, bx, HH);
    } else if (bx < NWG1 + NWG2) {
        lstm_role<9,9,1,2>(red, cst, nullptr, bias2, wih2, whh2,
                           h1A, h1B, h2A, h2B, nullptr,
                           h2o, c2o, arrive, bx - NWG1, HH);
    } else {
        lstm_role<9,4,2,4>(red, cst, nullptr, bias3, wih3, whh3,
                           h2A, h2B, h3A, h3B, xs3,
                           h3o, c3o, arrive, bx - NWG1 - NWG2, EE);
    }
}

// ---------------- host ----------------
extern "C" void kernel_launch(void* const* d_in, const int* in_sizes, int n_in,
                              void* d_out, int out_size, void* d_ws, size_t ws_size,
                              hipStream_t stream)
{
    const float* emb  = (const float*)d_in[0];
    const float* Wih1 = (const float*)d_in[1];
    const float* Whh1 = (const float*)d_in[2];
    const float* bih1 = (const float*)d_in[3];
    const float* bhh1 = (const float*)d_in[4];
    const float* Wih2 = (const float*)d_in[5];
    const float* Whh2 = (const float*)d_in[6];
    const float* bih2 = (const float*)d_in[7];
    const float* bhh2 = (const float*)d_in[8];
    const float* Wih3 = (const float*)d_in[9];
    const float* Whh3 = (const float*)d_in[10];
    const float* bih3 = (const float*)d_in[11];
    const float* bhh3 = (const float*)d_in[12];
    const float* linb = (const float*)d_in[13];
    const int*   x    = (const int*)d_in[14];
    float* out = (float*)d_out;
    char*  ws  = (char*)d_ws;
    char*  outc = (char*)d_out;

    // ---- ws layout (zeroed region first: flags + 6 h ping-pong buffers) ----
    const size_t ARR  = 0;                          // 242*64 = 15488 B (round up region)
    const size_t H1A  = 21760;                      // 16*1152*2 = 36864 each
    const size_t H1B  = H1A + 36864;
    const size_t H2A  = H1B + 36864;
    const size_t H2B  = H2A + 36864;
    const size_t H3A  = H2B + 36864;                // 16*512*2 = 16384 each
    const size_t H3B  = H3A + 16384;
    const size_t ZEND = H3B + 16384;                // 201984 (256-aligned)
    size_t off = ZEND;
    auto alloc = [&](size_t bytes){ size_t r = off; off += (bytes + 255) & ~(size_t)255; return r; };
    const size_t EMBBF = alloc((size_t)VV*416*2);   // 26.6 MB
    const size_t XS0   = alloc((size_t)MM*416*2);   // embedded input, f16
    const size_t XS3   = alloc((size_t)MM*416*2);   // layer3 output, f16
    const size_t WIH1  = alloc((size_t)4608*416*2); // packed for pre-GEMM
    const size_t B1    = alloc((size_t)4608*4);
    const size_t B2    = alloc((size_t)4608*4);
    const size_t B3    = alloc((size_t)1664*4);

    f16* emb_bf = (f16*)(ws + EMBBF);
    f16* xs0    = (f16*)(ws + XS0);
    f16* xs3    = (f16*)(ws + XS3);
    f16* wih1p  = (f16*)(ws + WIH1);
    float* bias1 = (float*)(ws + B1);
    float* bias2 = (float*)(ws + B2);
    float* bias3 = (float*)(ws + B3);
    unsigned* arr = (unsigned*)(ws + ARR);

    // ---- big scratch lives in the (dead-until-final-GEMM) out buffer ----
    float* pre1 = out;                               // 2048*4608*4 = 37,748,736 B
    const size_t OW_HH1 = 37748736;                  // 4608*1152*2 = 10,616,832
    const size_t OW_IH2 = OW_HH1 + 10616832;
    const size_t OW_HH2 = OW_IH2 + 10616832;
    const size_t OW_IH3 = OW_HH2 + 10616832;         // 1664*1152*2 = 3,833,856
    const size_t OW_HH3 = OW_IH3 + 3833856;          // 1664*512*2  = 1,703,936
    f16* whh1p = (f16*)(outc + OW_HH1);
    f16* wih2p = (f16*)(outc + OW_IH2);
    f16* whh2p = (f16*)(outc + OW_HH2);
    f16* wih3p = (f16*)(outc + OW_IH3);
    f16* whh3p = (f16*)(outc + OW_HH3);

    float* H1O = out + 65536000;  float* H2O = H1O + 18400;  float* H3O = H2O + 18400;
    float* C1O = H3O + 6400;      float* C2O = C1O + 18400;  float* C3O = C2O + 18400;

    hipMemsetAsync(d_ws, 0, ZEND, stream);

    conv_emb    <<<dim3(2, VV), 256, 0, stream>>>(emb, emb_bf);
    embed_gather<<<dim3(2, MM), 256, 0, stream>>>(emb, x, xs0);

    // layer-1 input pre-GEMM (input known upfront; stays a throughput GEMM)
    conv_w   <<<dim3(2, 4608), 256, 0, stream>>>(Wih1, wih1p, HH, EE, 416);
    conv_bias<<<dim3(18),      256, 0, stream>>>(bih1, bhh1, bias1, HH, 4608);
    gemm16<0><<<dim3(36, 16),  256, 0, stream>>>(xs0, wih1p, bias1, pre1, 416, 4608);

    // pack all recurrent-phase weights/biases
    conv_w   <<<dim3(5, 4608), 256, 0, stream>>>(Whh1, whh1p, HH, HH, 1152);
    conv_w   <<<dim3(5, 4608), 256, 0, stream>>>(Wih2, wih2p, HH, HH, 1152);
    conv_w   <<<dim3(5, 4608), 256, 0, stream>>>(Whh2, whh2p, HH, HH, 1152);
    conv_w   <<<dim3(5, 1664), 256, 0, stream>>>(Wih3, wih3p, EE, HH, 1152);
    conv_w   <<<dim3(2, 1664), 256, 0, stream>>>(Whh3, whh3p, EE, EE, 512);
    conv_bias<<<dim3(18),      256, 0, stream>>>(bih2, bhh2, bias2, HH, 4608);
    conv_bias<<<dim3(7),       256, 0, stream>>>(bih3, bhh3, bias3, EE, 1664);

    // pipelined 3-layer recurrence: 242 blocks, 1 per CU, 130 barrier steps
    lstm_mega<<<dim3(NWGT), 256, 0, stream>>>(
        pre1, bias2, bias3, whh1p, wih2p, whh2p, wih3p, whh3p,
        (f16*)(ws+H1A), (f16*)(ws+H1B), (f16*)(ws+H2A), (f16*)(ws+H2B),
        (f16*)(ws+H3A), (f16*)(ws+H3B),
        xs3, H1O, C1O, H2O, C2O, H3O, C3O, arr);

    // tied-weight logits with fused transpose to (B,V,T)
    gemm16<1><<<dim3(250, 16), 256, 0, stream>>>(xs3, emb_bf, linb, out, 416, 0);
}